// Round 1
// baseline (449.594 us; speedup 1.0000x reference)
//
#include <hip/hip_runtime.h>
#include <hip/hip_bf16.h>

#define NH 8
#define BB 4
#define NN 1024
#define DD 512
#define DH 64

typedef __bf16 bf16x8 __attribute__((ext_vector_type(8)));
typedef float f32x4 __attribute__((ext_vector_type(4)));

__device__ __forceinline__ unsigned short f2bf(float f) {
    union { float f; unsigned u; } v; v.f = f;
    unsigned u = v.u;
    unsigned r = u + 0x7FFFu + ((u >> 16) & 1u);   // RNE
    return (unsigned short)(r >> 16);
}

// ---- K0a: wv_eff[c][h] = sum_dh W[c, 2D + h*64+dh] * w_force[h*64+dh]; s_bias[h] likewise for b_proj
__global__ void k_wv(const float* __restrict__ W, const float* __restrict__ w_force,
                     const float* __restrict__ b_proj, float* __restrict__ wv_eff,
                     float* __restrict__ s_bias) {
    int t = blockIdx.x * blockDim.x + threadIdx.x;   // 0..4095
    int c = t >> 3, h = t & 7;
    float acc = 0.f;
    for (int dh = 0; dh < DH; ++dh)
        acc += W[c * (3 * DD) + 2 * DD + h * DH + dh] * w_force[h * DH + dh];
    wv_eff[c * 8 + h] = acc;
    if (t < 8) {
        float sb = 0.f;
        for (int dh = 0; dh < DH; ++dh)
            sb += b_proj[2 * DD + t * DH + dh] * w_force[t * DH + dh];
        s_bias[t] = sb;
    }
}

// ---- K0b: Wt[n][c] = bf16(W[c][n] * (n<512 ? 1/sqrt(512) : 1)); also bias_eff[n]
__global__ void k_wt(const float* __restrict__ W, const float* __restrict__ b_proj,
                     unsigned short* __restrict__ Wt, float* __restrict__ bias_eff) {
    __shared__ float tile[32][33];
    int c0 = blockIdx.x * 32;   // K dim (0..511)
    int n0 = blockIdx.y * 32;   // N dim (0..1023)
    int t = threadIdx.x;
    for (int i = 0; i < 4; ++i) {
        int idx = t + i * 256;
        int r = idx >> 5, cn = idx & 31;
        tile[r][cn] = W[(c0 + r) * (3 * DD) + n0 + cn];
    }
    __syncthreads();
    const float rscale = 0.044194173824159216f;   // 1/sqrt(512)
    for (int i = 0; i < 4; ++i) {
        int idx = t + i * 256;
        int nn = idx >> 5, cc = idx & 31;
        float v = tile[cc][nn];
        int n = n0 + nn;
        if (n < DD) v *= rscale;
        Wt[n * DD + c0 + cc] = f2bf(v);
    }
    if (blockIdx.x == 0 && t < 32) {
        int n = n0 + t;
        bias_eff[n] = b_proj[n] * (n < DD ? 0.044194173824159216f : 1.0f);
    }
}

// ---- K0c: emb fp32 -> bf16 bits
__global__ void k_emb(const float* __restrict__ emb, unsigned short* __restrict__ embb) {
    int t = blockIdx.x * blockDim.x + threadIdx.x;
    float4 v = ((const float4*)emb)[t];
    ushort4 o;
    o.x = f2bf(v.x); o.y = f2bf(v.y); o.z = f2bf(v.z); o.w = f2bf(v.w);
    ((ushort4*)embb)[t] = o;
}

// ---- Ks: s[b,h,j] = emb_row . wv_eff[:,h] + s_bias[h]   (fp32)
__global__ __launch_bounds__(256) void k_s(const float* __restrict__ emb,
                                           const float* __restrict__ wv_eff,
                                           const float* __restrict__ s_bias,
                                           float* __restrict__ s_ws) {
    __shared__ float wv[DD * 8];   // 16 KB
    int t = threadIdx.x;
    for (int i = 0; i < 16; ++i) wv[t + i * 256] = wv_eff[t + i * 256];
    __syncthreads();
    int wave = t >> 6, lane = t & 63;
    int row = blockIdx.x * 4 + wave;       // 0..4095 = b*1024 + j
    int c0 = lane * 8;
    float partial[8] = {0, 0, 0, 0, 0, 0, 0, 0};
    const float* er = emb + row * DD + c0;
    #pragma unroll
    for (int e = 0; e < 8; ++e) {
        float v = er[e];
        const float* wr = &wv[(c0 + e) * 8];
        #pragma unroll
        for (int h = 0; h < 8; ++h) partial[h] += v * wr[h];
    }
    float val = 0.f;
    #pragma unroll
    for (int h = 0; h < 8; ++h) {
        float p = partial[h];
        for (int off = 32; off; off >>= 1) p += __shfl_xor(p, off);
        if (lane == h) val = p;
    }
    if (lane < 8) {
        int b = row >> 10, j = row & 1023;
        s_ws[(b * 8 + lane) * NN + j] = val + s_bias[lane];
    }
}

// ---- GEMM1: [4096 x 512] bf16 @ Wt^T -> q (cols 0..511, pre-scaled) and k (cols 512..1023), bf16 out
__global__ __launch_bounds__(256) void k_gemm(const unsigned short* __restrict__ embb,
                                              const unsigned short* __restrict__ Wt,
                                              const float* __restrict__ bias_eff,
                                              unsigned short* __restrict__ qb,
                                              unsigned short* __restrict__ kb) {
    __shared__ __align__(16) unsigned short a_s[64 * 40];
    __shared__ __align__(16) unsigned short b_s[64 * 40];
    int m0 = blockIdx.x * 64, n0 = blockIdx.y * 64;
    int t = threadIdx.x;
    int wave = t >> 6, lane = t & 63;
    int wr = (wave >> 1) * 32, wc = (wave & 1) * 32;
    int qd = lane >> 4, l16 = lane & 15;
    int sr = t >> 2, sg = (t & 3) * 8;
    f32x4 acc[2][2] = {};
    for (int k0 = 0; k0 < DD; k0 += 32) {
        uint4 av = *(const uint4*)(embb + (m0 + sr) * DD + k0 + sg);
        uint4 bv = *(const uint4*)(Wt + (n0 + sr) * DD + k0 + sg);
        __syncthreads();
        *(uint4*)(&a_s[sr * 40 + sg]) = av;
        *(uint4*)(&b_s[sr * 40 + sg]) = bv;
        __syncthreads();
        bf16x8 af0 = *(const bf16x8*)(&a_s[(wr + l16) * 40 + qd * 8]);
        bf16x8 af1 = *(const bf16x8*)(&a_s[(wr + 16 + l16) * 40 + qd * 8]);
        bf16x8 bf0 = *(const bf16x8*)(&b_s[(wc + l16) * 40 + qd * 8]);
        bf16x8 bf1 = *(const bf16x8*)(&b_s[(wc + 16 + l16) * 40 + qd * 8]);
        acc[0][0] = __builtin_amdgcn_mfma_f32_16x16x32_bf16(af0, bf0, acc[0][0], 0, 0, 0);
        acc[0][1] = __builtin_amdgcn_mfma_f32_16x16x32_bf16(af0, bf1, acc[0][1], 0, 0, 0);
        acc[1][0] = __builtin_amdgcn_mfma_f32_16x16x32_bf16(af1, bf0, acc[1][0], 0, 0, 0);
        acc[1][1] = __builtin_amdgcn_mfma_f32_16x16x32_bf16(af1, bf1, acc[1][1], 0, 0, 0);
    }
    #pragma unroll
    for (int mi = 0; mi < 2; ++mi)
        #pragma unroll
        for (int ni = 0; ni < 2; ++ni) {
            int col = n0 + wc + ni * 16 + l16;
            float be = bias_eff[col];
            #pragma unroll
            for (int r = 0; r < 4; ++r) {
                int row = m0 + wr + mi * 16 + qd * 4 + r;
                unsigned short bvv = f2bf(acc[mi][ni][r] + be);
                if (col < DD) qb[row * DD + col] = bvv;
                else          kb[row * DD + col - DD] = bvv;
            }
        }
}

// ---- K2: fused attention: scores=QK^T+mask, exp (no max needed: |score|<~4), accumulate dirs*s, normalize
__global__ __launch_bounds__(512) void k_attn(const unsigned short* __restrict__ qb,
                                              const unsigned short* __restrict__ kb,
                                              const float* __restrict__ s_ws,
                                              const float* __restrict__ d_mask,
                                              const float* __restrict__ dirs,
                                              const float* __restrict__ b_force,
                                              float* __restrict__ out) {
    int b = blockIdx.x >> 6;
    int i0 = (blockIdx.x & 63) * 16;
    int t = threadIdx.x;
    int h = t >> 6, lane = t & 63;
    int qd = lane >> 4, c = lane & 15;

    const unsigned short* qbase = qb + ((b * NN + i0 + c) * DD + h * DH + qd * 8);
    bf16x8 aq0 = *(const bf16x8*)(qbase);
    bf16x8 aq1 = *(const bf16x8*)(qbase + 32);

    float acc[4][3] = {};
    float l[4] = {0, 0, 0, 0};
    const float* sm = s_ws + (b * 8 + h) * NN;
    const float* mbase = d_mask + (size_t)(b * 8 + h) * NN * NN;
    const float* dbase = dirs + (size_t)b * NN * NN * 3;

    for (int j0 = 0; j0 < NN; j0 += 16) {
        const unsigned short* kba = kb + ((b * NN + j0 + c) * DD + h * DH + qd * 8);
        bf16x8 bk0 = *(const bf16x8*)(kba);
        bf16x8 bk1 = *(const bf16x8*)(kba + 32);
        f32x4 sc = {0.f, 0.f, 0.f, 0.f};
        sc = __builtin_amdgcn_mfma_f32_16x16x32_bf16(aq0, bk0, sc, 0, 0, 0);
        sc = __builtin_amdgcn_mfma_f32_16x16x32_bf16(aq1, bk1, sc, 0, 0, 0);
        float sj = sm[j0 + c];
        #pragma unroll
        for (int r = 0; r < 4; ++r) {
            int i = i0 + qd * 4 + r;
            float sv = sc[r] + mbase[(size_t)i * NN + j0 + c];
            float p = __expf(sv);
            l[r] += p;
            float ts = p * sj;
            const float* dp = dbase + ((size_t)i * NN + (j0 + c)) * 3;
            acc[r][0] += ts * dp[0];
            acc[r][1] += ts * dp[1];
            acc[r][2] += ts * dp[2];
        }
    }
    // reduce over the 16 lanes of each quad (they share rows i=qd*4+r)
    #pragma unroll
    for (int r = 0; r < 4; ++r) {
        #pragma unroll
        for (int off = 1; off < 16; off <<= 1) {
            l[r] += __shfl_xor(l[r], off);
            acc[r][0] += __shfl_xor(acc[r][0], off);
            acc[r][1] += __shfl_xor(acc[r][1], off);
            acc[r][2] += __shfl_xor(acc[r][2], off);
        }
    }
    __shared__ float o_s[NH][16][3];
    if (c == 0) {
        #pragma unroll
        for (int r = 0; r < 4; ++r) {
            float inv = 1.0f / l[r];
            o_s[h][qd * 4 + r][0] = acc[r][0] * inv;
            o_s[h][qd * 4 + r][1] = acc[r][1] * inv;
            o_s[h][qd * 4 + r][2] = acc[r][2] * inv;
        }
    }
    __syncthreads();
    if (t < 48) {
        int i = t / 3, a = t % 3;
        float sum = b_force[0];
        #pragma unroll
        for (int hh = 0; hh < NH; ++hh) sum += o_s[hh][i][a];
        out[(size_t)(b * NN + i0 + i) * 3 + a] = sum;
    }
}

extern "C" void kernel_launch(void* const* d_in, const int* in_sizes, int n_in,
                              void* d_out, int out_size, void* d_ws, size_t ws_size,
                              hipStream_t stream) {
    (void)in_sizes; (void)n_in; (void)out_size; (void)ws_size;
    const float* emb     = (const float*)d_in[0];
    const float* dirs    = (const float*)d_in[1];
    const float* d_mask  = (const float*)d_in[2];
    const float* W       = (const float*)d_in[3];
    const float* b_proj  = (const float*)d_in[4];
    const float* w_force = (const float*)d_in[5];
    const float* b_force = (const float*)d_in[6];
    float* out = (float*)d_out;

    char* ws = (char*)d_ws;
    float* wv_eff   = (float*)ws;                       // 4096
    float* s_bias   = wv_eff + 4096;                    // 8
    float* bias_eff = s_bias + 8;                       // 1024
    float* s_ws     = bias_eff + 1024;                  // 32768
    unsigned short* Wt   = (unsigned short*)(s_ws + 32768);  // 512K elems
    unsigned short* embb = Wt + 1024 * 512;             // 2M elems
    unsigned short* qb   = embb + 4096 * 512;           // 2M elems
    unsigned short* kb   = qb + 4096 * 512;             // 2M elems
    // total ws: ~13.8 MB

    hipLaunchKernelGGL(k_wv,   dim3(16),      dim3(256), 0, stream, W, w_force, b_proj, wv_eff, s_bias);
    hipLaunchKernelGGL(k_wt,   dim3(16, 32),  dim3(256), 0, stream, W, b_proj, Wt, bias_eff);
    hipLaunchKernelGGL(k_emb,  dim3(2048),    dim3(256), 0, stream, emb, embb);
    hipLaunchKernelGGL(k_s,    dim3(1024),    dim3(256), 0, stream, emb, wv_eff, s_bias, s_ws);
    hipLaunchKernelGGL(k_gemm, dim3(64, 16),  dim3(256), 0, stream, embb, Wt, bias_eff, qb, kb);
    hipLaunchKernelGGL(k_attn, dim3(256),     dim3(512), 0, stream, qb, kb, s_ws, d_mask, dirs, b_force, out);
}

// Round 2
// 351.392 us; speedup vs baseline: 1.2795x; 1.2795x over previous
//
#include <hip/hip_runtime.h>
#include <hip/hip_bf16.h>

#define NH 8
#define BB 4
#define NN 1024
#define DD 512
#define DH 64
#define JSPLIT 4

typedef __bf16 bf16x8 __attribute__((ext_vector_type(8)));
typedef float f32x4 __attribute__((ext_vector_type(4)));

__device__ __forceinline__ unsigned short f2bf(float f) {
    union { float f; unsigned u; } v; v.f = f;
    unsigned u = v.u;
    unsigned r = u + 0x7FFFu + ((u >> 16) & 1u);   // RNE
    return (unsigned short)(r >> 16);
}

// ---- K0a: wv_eff[c][h] = sum_dh W[c, 2D + h*64+dh] * w_force[h*64+dh]; s_bias[h] likewise for b_proj
__global__ void k_wv(const float* __restrict__ W, const float* __restrict__ w_force,
                     const float* __restrict__ b_proj, float* __restrict__ wv_eff,
                     float* __restrict__ s_bias) {
    int t = blockIdx.x * blockDim.x + threadIdx.x;   // 0..4095
    int c = t >> 3, h = t & 7;
    float acc = 0.f;
    for (int dh = 0; dh < DH; ++dh)
        acc += W[c * (3 * DD) + 2 * DD + h * DH + dh] * w_force[h * DH + dh];
    wv_eff[c * 8 + h] = acc;
    if (t < 8) {
        float sb = 0.f;
        for (int dh = 0; dh < DH; ++dh)
            sb += b_proj[2 * DD + t * DH + dh] * w_force[t * DH + dh];
        s_bias[t] = sb;
    }
}

// ---- K0b: Wt[n][c] = bf16(W[c][n] * (n<512 ? 1/sqrt(512) : 1)); also bias_eff[n]
__global__ void k_wt(const float* __restrict__ W, const float* __restrict__ b_proj,
                     unsigned short* __restrict__ Wt, float* __restrict__ bias_eff) {
    __shared__ float tile[32][33];
    int c0 = blockIdx.x * 32;   // K dim (0..511)
    int n0 = blockIdx.y * 32;   // N dim (0..1023)
    int t = threadIdx.x;
    for (int i = 0; i < 4; ++i) {
        int idx = t + i * 256;
        int r = idx >> 5, cn = idx & 31;
        tile[r][cn] = W[(c0 + r) * (3 * DD) + n0 + cn];
    }
    __syncthreads();
    const float rscale = 0.044194173824159216f;   // 1/sqrt(512)
    for (int i = 0; i < 4; ++i) {
        int idx = t + i * 256;
        int nn = idx >> 5, cc = idx & 31;
        float v = tile[cc][nn];
        int n = n0 + nn;
        if (n < DD) v *= rscale;
        Wt[n * DD + c0 + cc] = f2bf(v);
    }
    if (blockIdx.x == 0 && t < 32) {
        int n = n0 + t;
        bias_eff[n] = b_proj[n] * (n < DD ? 0.044194173824159216f : 1.0f);
    }
}

// ---- K0c: emb fp32 -> bf16 bits
__global__ void k_emb(const float* __restrict__ emb, unsigned short* __restrict__ embb) {
    int t = blockIdx.x * blockDim.x + threadIdx.x;
    float4 v = ((const float4*)emb)[t];
    ushort4 o;
    o.x = f2bf(v.x); o.y = f2bf(v.y); o.z = f2bf(v.z); o.w = f2bf(v.w);
    ((ushort4*)embb)[t] = o;
}

// ---- Ks: s[b,h,j] = emb_row . wv_eff[:,h] + s_bias[h]   (fp32)
__global__ __launch_bounds__(256) void k_s(const float* __restrict__ emb,
                                           const float* __restrict__ wv_eff,
                                           const float* __restrict__ s_bias,
                                           float* __restrict__ s_ws) {
    __shared__ float wv[DD * 8];   // 16 KB
    int t = threadIdx.x;
    for (int i = 0; i < 16; ++i) wv[t + i * 256] = wv_eff[t + i * 256];
    __syncthreads();
    int wave = t >> 6, lane = t & 63;
    int row = blockIdx.x * 4 + wave;       // 0..4095 = b*1024 + j
    int c0 = lane * 8;
    float partial[8] = {0, 0, 0, 0, 0, 0, 0, 0};
    const float* er = emb + row * DD + c0;
    #pragma unroll
    for (int e = 0; e < 8; ++e) {
        float v = er[e];
        const float* wr = &wv[(c0 + e) * 8];
        #pragma unroll
        for (int h = 0; h < 8; ++h) partial[h] += v * wr[h];
    }
    float val = 0.f;
    #pragma unroll
    for (int h = 0; h < 8; ++h) {
        float p = partial[h];
        for (int off = 32; off; off >>= 1) p += __shfl_xor(p, off);
        if (lane == h) val = p;
    }
    if (lane < 8) {
        int b = row >> 10, j = row & 1023;
        s_ws[(b * 8 + lane) * NN + j] = val + s_bias[lane];
    }
}

// ---- GEMM1: [4096 x 512] bf16 @ Wt^T -> q (cols 0..511, pre-scaled) and k (cols 512..1023), bf16 out
__global__ __launch_bounds__(256) void k_gemm(const unsigned short* __restrict__ embb,
                                              const unsigned short* __restrict__ Wt,
                                              const float* __restrict__ bias_eff,
                                              unsigned short* __restrict__ qb,
                                              unsigned short* __restrict__ kb) {
    __shared__ __align__(16) unsigned short a_s[64 * 40];
    __shared__ __align__(16) unsigned short b_s[64 * 40];
    int m0 = blockIdx.x * 64, n0 = blockIdx.y * 64;
    int t = threadIdx.x;
    int wave = t >> 6, lane = t & 63;
    int wr = (wave >> 1) * 32, wc = (wave & 1) * 32;
    int qd = lane >> 4, l16 = lane & 15;
    int sr = t >> 2, sg = (t & 3) * 8;
    f32x4 acc[2][2] = {};
    for (int k0 = 0; k0 < DD; k0 += 32) {
        uint4 av = *(const uint4*)(embb + (m0 + sr) * DD + k0 + sg);
        uint4 bv = *(const uint4*)(Wt + (n0 + sr) * DD + k0 + sg);
        __syncthreads();
        *(uint4*)(&a_s[sr * 40 + sg]) = av;
        *(uint4*)(&b_s[sr * 40 + sg]) = bv;
        __syncthreads();
        bf16x8 af0 = *(const bf16x8*)(&a_s[(wr + l16) * 40 + qd * 8]);
        bf16x8 af1 = *(const bf16x8*)(&a_s[(wr + 16 + l16) * 40 + qd * 8]);
        bf16x8 bf0 = *(const bf16x8*)(&b_s[(wc + l16) * 40 + qd * 8]);
        bf16x8 bf1 = *(const bf16x8*)(&b_s[(wc + 16 + l16) * 40 + qd * 8]);
        acc[0][0] = __builtin_amdgcn_mfma_f32_16x16x32_bf16(af0, bf0, acc[0][0], 0, 0, 0);
        acc[0][1] = __builtin_amdgcn_mfma_f32_16x16x32_bf16(af0, bf1, acc[0][1], 0, 0, 0);
        acc[1][0] = __builtin_amdgcn_mfma_f32_16x16x32_bf16(af1, bf0, acc[1][0], 0, 0, 0);
        acc[1][1] = __builtin_amdgcn_mfma_f32_16x16x32_bf16(af1, bf1, acc[1][1], 0, 0, 0);
    }
    #pragma unroll
    for (int mi = 0; mi < 2; ++mi)
        #pragma unroll
        for (int ni = 0; ni < 2; ++ni) {
            int col = n0 + wc + ni * 16 + l16;
            float be = bias_eff[col];
            #pragma unroll
            for (int r = 0; r < 4; ++r) {
                int row = m0 + wr + mi * 16 + qd * 4 + r;
                unsigned short bvv = f2bf(acc[mi][ni][r] + be);
                if (col < DD) qb[row * DD + col] = bvv;
                else          kb[row * DD + col - DD] = bvv;
            }
        }
}

// ---- K2: fused attention, TRANSPOSED scores (row=j, col=i) for vectorized mask/dirs loads.
// Grid: (chunk*BB + b) * 64 + itile; 512 threads = 8 waves = 8 heads. No LDS, no barriers.
// Each thread: i = i0 + (lane&15), j = j0 + (lane>>4)*4 + r. Partials (l,acc3) per (chunk,b,h,i).
__global__ __launch_bounds__(512) void k_attn(const unsigned short* __restrict__ qb,
                                              const unsigned short* __restrict__ kb,
                                              const float* __restrict__ s_ws,
                                              const float* __restrict__ d_mask,
                                              const float* __restrict__ dirs,
                                              float4* __restrict__ part) {
    int blk = blockIdx.x;
    int itile = blk & 63;
    int bc = blk >> 6;           // chunk*BB + b, 0..15
    int b = bc & 3;
    int chunk = bc >> 2;
    int i0 = itile * 16;
    int j_base = chunk * (NN / JSPLIT);
    int t = threadIdx.x;
    int h = t >> 6, lane = t & 63;
    int qd = lane >> 4, c = lane & 15;
    int i = i0 + c;

    const unsigned short* qbase = qb + ((b * NN + i) * DD + h * DH + qd * 8);
    bf16x8 aq0 = *(const bf16x8*)(qbase);
    bf16x8 aq1 = *(const bf16x8*)(qbase + 32);

    float acc0 = 0.f, acc1 = 0.f, acc2 = 0.f, l = 0.f;
    const float* sm   = s_ws + (b * NH + h) * NN;
    const float* mrow = d_mask + (size_t)(b * NH + h) * NN * NN + (size_t)i * NN;
    const float* drow = dirs + ((size_t)b * NN + i) * NN * 3;

    for (int j0 = j_base; j0 < j_base + NN / JSPLIT; j0 += 16) {
        const unsigned short* kba = kb + ((b * NN + j0 + c) * DD + h * DH + qd * 8);
        bf16x8 bk0 = *(const bf16x8*)(kba);
        bf16x8 bk1 = *(const bf16x8*)(kba + 32);
        f32x4 sc = {0.f, 0.f, 0.f, 0.f};
        sc = __builtin_amdgcn_mfma_f32_16x16x32_bf16(bk0, aq0, sc, 0, 0, 0);
        sc = __builtin_amdgcn_mfma_f32_16x16x32_bf16(bk1, aq1, sc, 0, 0, 0);
        int jq = j0 + qd * 4;
        float4 mk = *(const float4*)(mrow + jq);
        float4 sj = *(const float4*)(sm + jq);
        float4 d0 = *(const float4*)(drow + jq * 3);
        float4 d1 = *(const float4*)(drow + jq * 3 + 4);
        float4 d2 = *(const float4*)(drow + jq * 3 + 8);
        float p0 = __expf(sc[0] + mk.x);
        float p1 = __expf(sc[1] + mk.y);
        float p2 = __expf(sc[2] + mk.z);
        float p3 = __expf(sc[3] + mk.w);
        l += p0 + p1 + p2 + p3;
        float t0 = p0 * sj.x, t1 = p1 * sj.y, t2 = p2 * sj.z, t3 = p3 * sj.w;
        // dirs layout: j=jq+0 -> d0.xyz ; jq+1 -> d0.w d1.xy ; jq+2 -> d1.zw d2.x ; jq+3 -> d2.yzw
        acc0 += t0 * d0.x + t1 * d0.w + t2 * d1.z + t3 * d2.y;
        acc1 += t0 * d0.y + t1 * d1.x + t2 * d1.w + t3 * d2.z;
        acc2 += t0 * d0.z + t1 * d1.y + t2 * d2.x + t3 * d2.w;
    }
    // reduce over qd (lanes sharing same i): xor 16, 32
    l    += __shfl_xor(l, 16);    l    += __shfl_xor(l, 32);
    acc0 += __shfl_xor(acc0, 16); acc0 += __shfl_xor(acc0, 32);
    acc1 += __shfl_xor(acc1, 16); acc1 += __shfl_xor(acc1, 32);
    acc2 += __shfl_xor(acc2, 16); acc2 += __shfl_xor(acc2, 32);
    if (qd == 0) {
        float4 o; o.x = l; o.y = acc0; o.z = acc1; o.w = acc2;
        part[((size_t)bc * NH + h) * NN + i] = o;
    }
}

// ---- K3: combine partials: out[b,i,a] = b_force + sum_h (sum_ch acc)/(sum_ch l)
__global__ __launch_bounds__(256) void k_fin(const float4* __restrict__ part,
                                             const float* __restrict__ b_force,
                                             float* __restrict__ out) {
    int t = blockIdx.x * 256 + threadIdx.x;   // 0..4095
    int b = t >> 10, i = t & 1023;
    float o0, o1, o2;
    o0 = o1 = o2 = b_force[0];
    #pragma unroll
    for (int h = 0; h < NH; ++h) {
        float lx = 0.f, a0 = 0.f, a1 = 0.f, a2 = 0.f;
        #pragma unroll
        for (int ch = 0; ch < JSPLIT; ++ch) {
            float4 p = part[(((size_t)(ch * BB + b) * NH + h) * NN) + i];
            lx += p.x; a0 += p.y; a1 += p.z; a2 += p.w;
        }
        float inv = 1.0f / lx;
        o0 += a0 * inv; o1 += a1 * inv; o2 += a2 * inv;
    }
    out[t * 3 + 0] = o0;
    out[t * 3 + 1] = o1;
    out[t * 3 + 2] = o2;
}

extern "C" void kernel_launch(void* const* d_in, const int* in_sizes, int n_in,
                              void* d_out, int out_size, void* d_ws, size_t ws_size,
                              hipStream_t stream) {
    (void)in_sizes; (void)n_in; (void)out_size; (void)ws_size;
    const float* emb     = (const float*)d_in[0];
    const float* dirs    = (const float*)d_in[1];
    const float* d_mask  = (const float*)d_in[2];
    const float* W       = (const float*)d_in[3];
    const float* b_proj  = (const float*)d_in[4];
    const float* w_force = (const float*)d_in[5];
    const float* b_force = (const float*)d_in[6];
    float* out = (float*)d_out;

    char* ws = (char*)d_ws;
    float* wv_eff   = (float*)ws;                       // 4096
    float* s_bias   = wv_eff + 4096;                    // 8
    float* bias_eff = s_bias + 8;                       // 1024
    float* s_ws     = bias_eff + 1024;                  // 32768
    unsigned short* Wt   = (unsigned short*)(s_ws + 32768);  // 512K elems
    unsigned short* embb = Wt + 1024 * 512;             // 2M elems
    unsigned short* qb   = embb + 4096 * 512;           // 2M elems
    unsigned short* kb   = qb + 4096 * 512;             // 2M elems
    float4* part = (float4*)(kb + 4096 * 512);          // 16*8*1024 float4 = 2 MB
    // total ws: ~15.9 MB

    hipLaunchKernelGGL(k_wv,   dim3(16),      dim3(256), 0, stream, W, w_force, b_proj, wv_eff, s_bias);
    hipLaunchKernelGGL(k_wt,   dim3(16, 32),  dim3(256), 0, stream, W, b_proj, Wt, bias_eff);
    hipLaunchKernelGGL(k_emb,  dim3(2048),    dim3(256), 0, stream, emb, embb);
    hipLaunchKernelGGL(k_s,    dim3(1024),    dim3(256), 0, stream, emb, wv_eff, s_bias, s_ws);
    hipLaunchKernelGGL(k_gemm, dim3(64, 16),  dim3(256), 0, stream, embb, Wt, bias_eff, qb, kb);
    hipLaunchKernelGGL(k_attn, dim3(BB * 64 * JSPLIT), dim3(512), 0, stream,
                       qb, kb, s_ws, d_mask, dirs, part);
    hipLaunchKernelGGL(k_fin,  dim3(16),      dim3(256), 0, stream, part, b_force, out);
}

// Round 4
// 344.022 us; speedup vs baseline: 1.3069x; 1.0214x over previous
//
#include <hip/hip_runtime.h>
#include <hip/hip_bf16.h>

#define NH 8
#define BB 4
#define NN 1024
#define DD 512
#define DH 64
#define JSPLIT 4

typedef __bf16 bf16x8 __attribute__((ext_vector_type(8)));
typedef float f32x4 __attribute__((ext_vector_type(4)));

__device__ __forceinline__ unsigned short f2bf(float f) {
    union { float f; unsigned u; } v; v.f = f;
    unsigned u = v.u;
    unsigned r = u + 0x7FFFu + ((u >> 16) & 1u);   // RNE
    return (unsigned short)(r >> 16);
}

// ---- k_wv: wv_eff[c][h] = sum_dh W[c, 2D+h*64+dh]*w_force[h*64+dh]. Wave per c (512 rows
// -> 128 blocks of 4 waves). Block 128 handles s_bias (same reduction on b_proj).
__global__ __launch_bounds__(256) void k_wv(const float* __restrict__ W, const float* __restrict__ w_force,
                                            const float* __restrict__ b_proj, float* __restrict__ wv_eff,
                                            float* __restrict__ s_bias) {
    int wave = threadIdx.x >> 6, lane = threadIdx.x & 63;
    if (blockIdx.x == 128) {
        if (wave == 0) {
            for (int hh = 0; hh < NH; ++hh) {
                float p = b_proj[2 * DD + hh * DH + lane] * w_force[hh * DH + lane];
                for (int off = 32; off; off >>= 1) p += __shfl_xor(p, off);
                if (lane == 0) s_bias[hh] = p;
            }
        }
        return;
    }
    int c = blockIdx.x * 4 + wave;   // 0..511
    const float* wr = W + (size_t)c * (3 * DD) + 2 * DD;
    #pragma unroll
    for (int hh = 0; hh < NH; ++hh) {
        float p = wr[hh * DH + lane] * w_force[hh * DH + lane];
        for (int off = 32; off; off >>= 1) p += __shfl_xor(p, off);
        if (lane == 0) wv_eff[c * 8 + hh] = p;
    }
}

// ---- k_wt: Wt[n][c] = bf16(W[c][n] * (n<512 ? 1/sqrt(512) : 1)); also bias_eff[n]
__global__ void k_wt(const float* __restrict__ W, const float* __restrict__ b_proj,
                     unsigned short* __restrict__ Wt, float* __restrict__ bias_eff) {
    __shared__ float tile[32][33];
    int c0 = blockIdx.x * 32;   // K dim (0..511)
    int n0 = blockIdx.y * 32;   // N dim (0..1023)
    int t = threadIdx.x;
    for (int i = 0; i < 4; ++i) {
        int idx = t + i * 256;
        int r = idx >> 5, cn = idx & 31;
        tile[r][cn] = W[(c0 + r) * (3 * DD) + n0 + cn];
    }
    __syncthreads();
    const float rscale = 0.044194173824159216f;   // 1/sqrt(512)
    for (int i = 0; i < 4; ++i) {
        int idx = t + i * 256;
        int nn = idx >> 5, cc = idx & 31;
        float v = tile[cc][nn];
        int n = n0 + nn;
        if (n < DD) v *= rscale;
        Wt[n * DD + c0 + cc] = f2bf(v);
    }
    if (blockIdx.x == 0 && t < 32) {
        int n = n0 + t;
        bias_eff[n] = b_proj[n] * (n < DD ? 0.044194173824159216f : 1.0f);
    }
}

// ---- k_emb: emb fp32 -> bf16 bits
__global__ void k_emb(const float* __restrict__ emb, unsigned short* __restrict__ embb) {
    int t = blockIdx.x * blockDim.x + threadIdx.x;
    float4 v = ((const float4*)emb)[t];
    ushort4 o;
    o.x = f2bf(v.x); o.y = f2bf(v.y); o.z = f2bf(v.z); o.w = f2bf(v.w);
    ((ushort4*)embb)[t] = o;
}

// ---- k_s: thread per (row,h). emb row broadcast across 8 h-lanes; wv_eff reads coalesced. No LDS.
__global__ __launch_bounds__(256) void k_s(const float* __restrict__ emb,
                                           const float* __restrict__ wv_eff,
                                           const float* __restrict__ s_bias,
                                           float* __restrict__ s_ws) {
    int t = blockIdx.x * 256 + threadIdx.x;   // 0..32767
    int row = t >> 3;                          // b*1024 + j
    int h = t & 7;
    const float* er = emb + (size_t)row * DD;
    const float* wp = wv_eff + h;
    float acc = 0.f;
    #pragma unroll 8
    for (int c4 = 0; c4 < DD / 4; ++c4) {
        float4 e = *(const float4*)(er + c4 * 4);
        acc += e.x * wp[(c4 * 4 + 0) * 8];
        acc += e.y * wp[(c4 * 4 + 1) * 8];
        acc += e.z * wp[(c4 * 4 + 2) * 8];
        acc += e.w * wp[(c4 * 4 + 3) * 8];
    }
    int b = row >> 10, j = row & 1023;
    s_ws[(b * 8 + h) * NN + j] = acc + s_bias[h];
}

// ---- k_gemm: 128x128 tile, 4 waves, 4x4 accs/wave (m93 recipe). M=4096, N=1024, K=512.
__global__ __launch_bounds__(256) void k_gemm(const unsigned short* __restrict__ embb,
                                              const unsigned short* __restrict__ Wt,
                                              const float* __restrict__ bias_eff,
                                              unsigned short* __restrict__ qb,
                                              unsigned short* __restrict__ kb) {
    __shared__ __align__(16) unsigned short a_s[128 * 32];
    __shared__ __align__(16) unsigned short b_s[128 * 32];
    int m0 = blockIdx.x * 128, n0 = blockIdx.y * 128;
    int t = threadIdx.x;
    int wave = t >> 6, lane = t & 63;
    int wr = (wave >> 1) * 64, wc = (wave & 1) * 64;
    int qd = lane >> 4, c = lane & 15;
    int sr = t >> 2, sg = (t & 3) * 8;
    f32x4 acc[4][4] = {};
    for (int k0 = 0; k0 < DD; k0 += 32) {
        uint4 av0 = *(const uint4*)(embb + (size_t)(m0 + sr) * DD + k0 + sg);
        uint4 av1 = *(const uint4*)(embb + (size_t)(m0 + 64 + sr) * DD + k0 + sg);
        uint4 bv0 = *(const uint4*)(Wt + (size_t)(n0 + sr) * DD + k0 + sg);
        uint4 bv1 = *(const uint4*)(Wt + (size_t)(n0 + 64 + sr) * DD + k0 + sg);
        __syncthreads();
        *(uint4*)(&a_s[sr * 32 + sg]) = av0;
        *(uint4*)(&a_s[(64 + sr) * 32 + sg]) = av1;
        *(uint4*)(&b_s[sr * 32 + sg]) = bv0;
        *(uint4*)(&b_s[(64 + sr) * 32 + sg]) = bv1;
        __syncthreads();
        bf16x8 af[4], bfr[4];
        #pragma unroll
        for (int mi = 0; mi < 4; ++mi)
            af[mi] = *(const bf16x8*)(&a_s[(wr + mi * 16 + c) * 32 + qd * 8]);
        #pragma unroll
        for (int ni = 0; ni < 4; ++ni)
            bfr[ni] = *(const bf16x8*)(&b_s[(wc + ni * 16 + c) * 32 + qd * 8]);
        #pragma unroll
        for (int mi = 0; mi < 4; ++mi)
            #pragma unroll
            for (int ni = 0; ni < 4; ++ni)
                acc[mi][ni] = __builtin_amdgcn_mfma_f32_16x16x32_bf16(af[mi], bfr[ni], acc[mi][ni], 0, 0, 0);
    }
    bool isQ = (n0 < DD);
    unsigned short* dst = isQ ? qb : kb;
    int nb = isQ ? n0 : n0 - DD;
    #pragma unroll
    for (int mi = 0; mi < 4; ++mi)
        #pragma unroll
        for (int ni = 0; ni < 4; ++ni) {
            int col = nb + wc + ni * 16 + c;
            float be = bias_eff[isQ ? col : col + DD];
            #pragma unroll
            for (int r = 0; r < 4; ++r) {
                int row = m0 + wr + mi * 16 + qd * 4 + r;
                dst[(size_t)row * DD + col] = f2bf(acc[mi][ni][r] + be);
            }
        }
}

// ---- k_attn: transposed-score fused attention with explicit register pipeline.
// Block = 256 thr = 4 waves = 4 heads; grid covers (chunk, b, hgroup, itile).
__global__ __launch_bounds__(256) void k_attn(const unsigned short* __restrict__ qb,
                                              const unsigned short* __restrict__ kb,
                                              const float* __restrict__ s_ws,
                                              const float* __restrict__ d_mask,
                                              const float* __restrict__ dirs,
                                              float* __restrict__ part) {
    int blk = blockIdx.x;
    int itile = blk & 63;
    int rest = blk >> 6;             // 0..31
    int hg = rest & 1;
    int b = (rest >> 1) & 3;
    int chunk = rest >> 3;           // 0..3
    int i0 = itile * 16;
    int j_base = chunk * (NN / JSPLIT);
    int t = threadIdx.x;
    int h = hg * 4 + (t >> 6);
    int lane = t & 63, qd = lane >> 4, c = lane & 15;
    int i = i0 + c;

    const unsigned short* qbase = qb + ((size_t)(b * NN + i) * DD + h * DH + qd * 8);
    bf16x8 aq0 = *(const bf16x8*)(qbase);
    bf16x8 aq1 = *(const bf16x8*)(qbase + 32);

    const unsigned short* kp = kb + ((size_t)(b * NN + j_base + c) * DD + h * DH + qd * 8);
    const float* mp = d_mask + (size_t)(b * NH + h) * NN * NN + (size_t)i * NN + j_base + qd * 4;
    const float* sp = s_ws + (b * NH + h) * NN + j_base + qd * 4;
    const float* dp = dirs + (((size_t)b * NN + i) * NN + j_base + qd * 4) * 3;

    float acc0 = 0.f, acc1 = 0.f, acc2 = 0.f, l = 0.f;

    // prologue: load iteration 0
    bf16x8 ck0 = *(const bf16x8*)(kp);
    bf16x8 ck1 = *(const bf16x8*)(kp + 32);
    f32x4 cmk = __builtin_nontemporal_load((const f32x4*)mp);
    f32x4 csj = *(const f32x4*)sp;
    f32x4 cd0 = *(const f32x4*)(dp);
    f32x4 cd1 = *(const f32x4*)(dp + 4);
    f32x4 cd2 = *(const f32x4*)(dp + 8);

    auto step = [&](bf16x8 k0, bf16x8 k1, f32x4 mk, f32x4 sj, f32x4 d0, f32x4 d1, f32x4 d2) {
        f32x4 sc = {0.f, 0.f, 0.f, 0.f};
        sc = __builtin_amdgcn_mfma_f32_16x16x32_bf16(k0, aq0, sc, 0, 0, 0);
        sc = __builtin_amdgcn_mfma_f32_16x16x32_bf16(k1, aq1, sc, 0, 0, 0);
        float p0 = __expf(sc[0] + mk.x);
        float p1 = __expf(sc[1] + mk.y);
        float p2 = __expf(sc[2] + mk.z);
        float p3 = __expf(sc[3] + mk.w);
        l += p0 + p1 + p2 + p3;
        float t0 = p0 * sj.x, t1 = p1 * sj.y, t2 = p2 * sj.z, t3 = p3 * sj.w;
        acc0 += t0 * d0.x + t1 * d0.w + t2 * d1.z + t3 * d2.y;
        acc1 += t0 * d0.y + t1 * d1.x + t2 * d1.w + t3 * d2.z;
        acc2 += t0 * d0.z + t1 * d1.y + t2 * d2.x + t3 * d2.w;
    };

    #pragma unroll
    for (int it = 0; it < NN / JSPLIT / 16 - 1; ++it) {
        kp += 16 * DD; mp += 16; sp += 16; dp += 48;
        bf16x8 nk0 = *(const bf16x8*)(kp);
        bf16x8 nk1 = *(const bf16x8*)(kp + 32);
        f32x4 nmk = __builtin_nontemporal_load((const f32x4*)mp);
        f32x4 nsj = *(const f32x4*)sp;
        f32x4 nd0 = *(const f32x4*)(dp);
        f32x4 nd1 = *(const f32x4*)(dp + 4);
        f32x4 nd2 = *(const f32x4*)(dp + 8);
        step(ck0, ck1, cmk, csj, cd0, cd1, cd2);
        ck0 = nk0; ck1 = nk1; cmk = nmk; csj = nsj; cd0 = nd0; cd1 = nd1; cd2 = nd2;
    }
    step(ck0, ck1, cmk, csj, cd0, cd1, cd2);   // epilogue iteration

    // reduce over qd (lanes sharing same i)
    l    += __shfl_xor(l, 16);    l    += __shfl_xor(l, 32);
    acc0 += __shfl_xor(acc0, 16); acc0 += __shfl_xor(acc0, 32);
    acc1 += __shfl_xor(acc1, 16); acc1 += __shfl_xor(acc1, 32);
    acc2 += __shfl_xor(acc2, 16); acc2 += __shfl_xor(acc2, 32);
    if (qd == 0) {
        f32x4 o; o[0] = l; o[1] = acc0; o[2] = acc1; o[3] = acc2;
        *(f32x4*)(part + ((((size_t)(chunk * BB + b)) * NH + h) * NN + i) * 4) = o;
    }
}

// ---- k_fin: out[b,i,a] = b_force + sum_h (sum_ch acc)/(sum_ch l)
__global__ __launch_bounds__(256) void k_fin(const float4* __restrict__ part,
                                             const float* __restrict__ b_force,
                                             float* __restrict__ out) {
    int t = blockIdx.x * 256 + threadIdx.x;   // 0..4095
    int b = t >> 10, i = t & 1023;
    float o0, o1, o2;
    o0 = o1 = o2 = b_force[0];
    #pragma unroll
    for (int h = 0; h < NH; ++h) {
        float lx = 0.f, a0 = 0.f, a1 = 0.f, a2 = 0.f;
        #pragma unroll
        for (int ch = 0; ch < JSPLIT; ++ch) {
            float4 p = part[(((size_t)(ch * BB + b) * NH + h) * NN) + i];
            lx += p.x; a0 += p.y; a1 += p.z; a2 += p.w;
        }
        float inv = 1.0f / lx;
        o0 += a0 * inv; o1 += a1 * inv; o2 += a2 * inv;
    }
    out[t * 3 + 0] = o0;
    out[t * 3 + 1] = o1;
    out[t * 3 + 2] = o2;
}

extern "C" void kernel_launch(void* const* d_in, const int* in_sizes, int n_in,
                              void* d_out, int out_size, void* d_ws, size_t ws_size,
                              hipStream_t stream) {
    (void)in_sizes; (void)n_in; (void)out_size; (void)ws_size;
    const float* emb     = (const float*)d_in[0];
    const float* dirs    = (const float*)d_in[1];
    const float* d_mask  = (const float*)d_in[2];
    const float* W       = (const float*)d_in[3];
    const float* b_proj  = (const float*)d_in[4];
    const float* w_force = (const float*)d_in[5];
    const float* b_force = (const float*)d_in[6];
    float* out = (float*)d_out;

    char* ws = (char*)d_ws;
    float* wv_eff   = (float*)ws;                       // 4096
    float* s_bias   = wv_eff + 4096;                    // 8
    float* bias_eff = s_bias + 8;                       // 1024
    float* s_ws     = bias_eff + 1024;                  // 32768
    unsigned short* Wt   = (unsigned short*)(s_ws + 32768);  // 512K elems
    unsigned short* embb = Wt + 1024 * 512;             // 2M elems
    unsigned short* qb   = embb + 4096 * 512;           // 2M elems
    unsigned short* kb   = qb + 4096 * 512;             // 2M elems
    float* part = (float*)(kb + 4096 * 512);            // 16*8*1024 float4 = 2 MB

    hipLaunchKernelGGL(k_wv,   dim3(129),     dim3(256), 0, stream, W, w_force, b_proj, wv_eff, s_bias);
    hipLaunchKernelGGL(k_wt,   dim3(16, 32),  dim3(256), 0, stream, W, b_proj, Wt, bias_eff);
    hipLaunchKernelGGL(k_emb,  dim3(2048),    dim3(256), 0, stream, emb, embb);
    hipLaunchKernelGGL(k_s,    dim3(128),     dim3(256), 0, stream, emb, wv_eff, s_bias, s_ws);
    hipLaunchKernelGGL(k_gemm, dim3(32, 8),   dim3(256), 0, stream, embb, Wt, bias_eff, qb, kb);
    hipLaunchKernelGGL(k_attn, dim3(BB * 64 * JSPLIT * 2), dim3(256), 0, stream,
                       qb, kb, s_ws, d_mask, dirs, part);
    hipLaunchKernelGGL(k_fin,  dim3(16),      dim3(256), 0, stream, (const float4*)part, b_force, out);
}